// Round 21
// baseline (108.558 us; speedup 1.0000x reference)
//
#include <hip/hip_runtime.h>
#include <math.h>

typedef __bf16 bf16;
typedef __attribute__((ext_vector_type(8))) __bf16 bf16x8;
typedef __attribute__((ext_vector_type(4))) __bf16 bf16x4;
typedef __attribute__((ext_vector_type(4))) float f32x4;

#define MFMA(a, b, c) __builtin_amdgcn_mfma_f32_16x16x32_bf16((a), (b), (c), 0, 0, 0)
#define BARR() __builtin_amdgcn_s_barrier()
#define SFEN() __builtin_amdgcn_sched_barrier(0)
#define WAITV(n) asm volatile("s_waitcnt vmcnt(" #n ")" ::: "memory")
#define LGKM0() asm volatile("s_waitcnt lgkmcnt(0)" ::: "memory")

static constexpr int NB = 16384;   // batch
static constexpr int NC = 512;     // feature dim
static constexpr int NH = 128;     // bottleneck
static constexpr int ND = 3;       // domains
static constexpr int NT = 1380;    // text rows
static constexpr int NTP = 1408;   // padded to 11 x 128
static constexpr int NTILE = 131;  // max 128-row packed tiles
static constexpr int NPMAX = NTILE * 128;

__device__ __forceinline__ void gld16(const bf16* g, void* l) {
  __builtin_amdgcn_global_load_lds(
      (const __attribute__((address_space(1))) void*)g,
      (__attribute__((address_space(3))) void*)l, 16, 0, 0);
}

// ---------------------------------------------------------------------------
// k_prep (merged prep + sort, 1024-thread blocks, 185 blocks — champion)
// ---------------------------------------------------------------------------
__global__ __launch_bounds__(1024) void k_prep(
    const float* __restrict__ W1, const float* __restrict__ W2,
    const float* __restrict__ txt, const int* __restrict__ lab,
    bf16* __restrict__ W1t, bf16* __restrict__ W2t, bf16* __restrict__ Tbf,
    int* __restrict__ map, int* __restrict__ dmeta)
{
  __shared__ float tl[64][65];
  __shared__ int woff[16][3];
  __shared__ int segbase[4];
  __shared__ int padded[3];
  const int b = blockIdx.x, t = threadIdx.x;

  if (b < 88) {
    const int wv = t >> 6, lane = t & 63;
    const int row = b * 16 + wv;
    bf16x4* dst = (bf16x4*)(Tbf + (size_t)row * NC);
    if (row < NT) {
      const float4* src = (const float4*)(txt + (size_t)row * NC);
      float4 u0 = src[lane * 2], u1 = src[lane * 2 + 1];
      float ssq = u0.x * u0.x + u0.y * u0.y + u0.z * u0.z + u0.w * u0.w +
                  u1.x * u1.x + u1.y * u1.y + u1.z * u1.z + u1.w * u1.w;
      for (int m = 32; m; m >>= 1) ssq += __shfl_xor(ssq, m, 64);
      float inv = 1.0f / sqrtf(ssq);
      bf16x4 o0 = {(bf16)(u0.x * inv), (bf16)(u0.y * inv), (bf16)(u0.z * inv), (bf16)(u0.w * inv)};
      bf16x4 o1 = {(bf16)(u1.x * inv), (bf16)(u1.y * inv), (bf16)(u1.z * inv), (bf16)(u1.w * inv)};
      dst[lane * 2] = o0; dst[lane * 2 + 1] = o1;
    } else {
      bf16x4 z = {(bf16)0.f, (bf16)0.f, (bf16)0.f, (bf16)0.f};
      dst[lane * 2] = z; dst[lane * 2 + 1] = z;
    }
  } else if (b < 136) {
    const int e = b - 88, d = e >> 4, rem = e & 15;
    const int i0 = (rem >> 1) * 64, n0 = (rem & 1) * 64;
    const int rr = t >> 4, c4 = (t & 15) * 4;
    const float* src = W1 + (size_t)d * NC * NH;
    float4 v = *(const float4*)&src[(size_t)(i0 + rr) * NH + n0 + c4];
    tl[rr][c4] = v.x; tl[rr][c4 + 1] = v.y; tl[rr][c4 + 2] = v.z; tl[rr][c4 + 3] = v.w;
    __syncthreads();
    bf16* dst = W1t + (size_t)d * NH * NC;
    bf16x4 o = {(bf16)tl[c4][rr], (bf16)tl[c4 + 1][rr],
                (bf16)tl[c4 + 2][rr], (bf16)tl[c4 + 3][rr]};
    *(bf16x4*)&dst[(size_t)(n0 + rr) * NC + i0 + c4] = o;
  } else if (b < 184) {
    const int e = b - 136, d = e >> 4, rem = e & 15;
    const int j0 = (rem >> 3) * 64, n0 = (rem & 7) * 64;
    const int rr = t >> 4, c4 = (t & 15) * 4;
    const float* src = W2 + (size_t)d * NH * NC;
    float4 v = *(const float4*)&src[(size_t)(j0 + rr) * NC + n0 + c4];
    tl[rr][c4] = v.x; tl[rr][c4 + 1] = v.y; tl[rr][c4 + 2] = v.z; tl[rr][c4 + 3] = v.w;
    __syncthreads();
    bf16* dst = W2t + (size_t)d * NC * NH;
    bf16x4 o = {(bf16)tl[c4][rr], (bf16)tl[c4 + 1][rr],
                (bf16)tl[c4 + 2][rr], (bf16)tl[c4 + 3][rr]};
    *(bf16x4*)&dst[(size_t)(n0 + rr) * NH + j0 + c4] = o;
  } else {
    const int lane = t & 63, wv = t >> 6;
    int c[3] = {0, 0, 0};
    int ld[16];
    const int base = t * 16;
#pragma unroll
    for (int i = 0; i < 16; ++i) { ld[i] = lab[base + i]; c[ld[i]]++; }
    int exc[3];
#pragma unroll
    for (int d = 0; d < 3; ++d) {
      int v = c[d];
      for (int off = 1; off < 64; off <<= 1) {
        int u = __shfl_up(v, off, 64);
        if (lane >= off) v += u;
      }
      exc[d] = v - c[d];
      if (lane == 63) woff[wv][d] = v;
    }
    __syncthreads();
    if (t == 0) {
      int tot[3] = {0, 0, 0};
      for (int w = 0; w < 16; ++w)
        for (int d = 0; d < 3; ++d) { int v = woff[w][d]; woff[w][d] = tot[d]; tot[d] += v; }
      int s = 0;
      for (int d = 0; d < 3; ++d) {
        padded[d] = (tot[d] + 127) & ~127;
        segbase[d] = s; s += padded[d];
      }
      segbase[3] = s;
      dmeta[NTILE] = s;
    }
    __syncthreads();
    for (int tile = t; tile < NTILE; tile += 1024) {
      const int slot = tile * 128;
      int dd = -1;
      for (int d = 0; d < 3; ++d)
        if (slot >= segbase[d] && slot < segbase[d] + padded[d]) dd = d;
      dmeta[tile] = dd;
    }
    for (int i = t; i < NPMAX; i += 1024) map[i] = -1;
    __syncthreads();
    int pos[3];
#pragma unroll
    for (int d = 0; d < 3; ++d) pos[d] = segbase[d] + woff[wv][d] + exc[d];
#pragma unroll
    for (int i = 0; i < 16; ++i) { int d = ld[i]; map[pos[d]++] = base + i; }
  }
}

// ---------------------------------------------------------------------------
// k_adapter (champion: 64-row tiles, 512 thr, 262 blocks, W1 prefetched).
// ---------------------------------------------------------------------------
__global__ __launch_bounds__(512) void k_adapter(
    const float* __restrict__ X, const bf16* __restrict__ W1t,
    const bf16* __restrict__ W2t, const int* __restrict__ map,
    const int* __restrict__ dmeta, bf16* __restrict__ Fbf)
{
  __shared__ bf16 As[2][64 * 64];
  __shared__ bf16 Hs[64 * 128];
  __shared__ float rssq[8][64];
  __shared__ int smap[64];
  const int bx = blockIdx.x;
  const int d = dmeta[bx >> 1];
  if (d < 0) return;
  const int t = threadIdx.x, w = t >> 6, l = t & 63;
  const int lr = l & 15, lg = l >> 4;
  const int row0 = bx * 64;
  if (t < 64) smap[t] = map[row0 + t];

  const bf16* W1B = W1t + (size_t)d * NH * NC + (size_t)(w * 16 + lr) * NC;
  bf16x8 w1f[16];
#pragma unroll
  for (int kt = 0; kt < 8; ++kt)
#pragma unroll
    for (int h = 0; h < 2; ++h)
      w1f[kt * 2 + h] = *(const bf16x8*)(W1B + kt * 64 + h * 32 + lg * 8);

  int arow = map[row0 + (t >> 3)]; if (arow < 0) arow = 0;
  const float4* Xr = (const float4*)(X + (size_t)arow * NC);
  const int f4b = (t & 7) * 2;
  const int wrow = t >> 3;
  const int wcb = ((t & 7) * 16) ^ ((wrow & 7) << 4);

  float4 R0a, R0b, R1a, R1b;
#define LOADR0(kt) { R0a = Xr[(kt) * 16 + f4b]; R0b = Xr[(kt) * 16 + f4b + 1]; }
#define LOADR1(kt) { R1a = Xr[(kt) * 16 + f4b]; R1b = Xr[(kt) * 16 + f4b + 1]; }
#define CVTW(buf, Ra, Rb) {                                                   \
    bf16x8 v_;                                                                \
    v_[0] = (bf16)Ra.x; v_[1] = (bf16)Ra.y; v_[2] = (bf16)Ra.z;               \
    v_[3] = (bf16)Ra.w; v_[4] = (bf16)Rb.x; v_[5] = (bf16)Rb.y;               \
    v_[6] = (bf16)Rb.z; v_[7] = (bf16)Rb.w;                                   \
    *(bf16x8*)((char*)As[buf] + wrow * 128 + wcb) = v_; }

  f32x4 acc1[4] = {};
  LOADR0(0); LOADR1(1);
  CVTW(0, R0a, R0b);
  LOADR0(2);
  LGKM0(); BARR(); SFEN();
#pragma unroll
  for (int kt = 0; kt < 8; ++kt) {
    const int cur = kt & 1;
    if (kt + 1 < 8) {
      if (cur == 0) { CVTW(1, R1a, R1b); if (kt + 3 < 8) LOADR1(kt + 3); }
      else          { CVTW(0, R0a, R0b); if (kt + 3 < 8) LOADR0(kt + 3); }
    }
#pragma unroll
    for (int h = 0; h < 2; ++h) {
      bf16x8 a[4];
#pragma unroll
      for (int m = 0; m < 4; ++m) {
        const int r = m * 16 + lr;
        a[m] = *(const bf16x8*)((const char*)As[cur] +
                                r * 128 + ((h * 64 + lg * 16) ^ ((r & 7) << 4)));
      }
#pragma unroll
      for (int m = 0; m < 4; ++m) acc1[m] = MFMA(a[m], w1f[kt * 2 + h], acc1[m]);
    }
    LGKM0(); SFEN(); BARR(); SFEN();
  }
#undef LOADR0
#undef LOADR1
#undef CVTW

#pragma unroll
  for (int m = 0; m < 4; ++m)
#pragma unroll
    for (int r = 0; r < 4; ++r) {
      const int row = m * 16 + lg * 4 + r;
      const int colb = (w * 16 + lr) * 2;
      const float v = acc1[m][r];
      *(bf16*)((char*)Hs + row * 256 + (colb ^ ((row & 7) << 4))) =
          (bf16)(v > 0.f ? v : 0.f);
    }
  __syncthreads();

  f32x4 acc[4][4] = {};
  const bf16* W2B = W2t + (size_t)d * NC * NH + (size_t)(w * 64) * NH;
#pragma unroll
  for (int ks = 0; ks < 4; ++ks) {
    bf16x8 a[4], bq[4];
#pragma unroll
    for (int m = 0; m < 4; ++m) {
      const int r = m * 16 + lr;
      a[m] = *(const bf16x8*)((const char*)Hs +
                              r * 256 + ((ks * 64 + lg * 16) ^ ((r & 7) << 4)));
    }
#pragma unroll
    for (int n = 0; n < 4; ++n)
      bq[n] = *(const bf16x8*)(W2B + (size_t)(n * 16 + lr) * NH + ks * 32 + lg * 8);
#pragma unroll
    for (int m = 0; m < 4; ++m)
#pragma unroll
      for (int n = 0; n < 4; ++n)
        acc[m][n] = MFMA(a[m], bq[n], acc[m][n]);
  }

  const int col0 = w * 64;
#pragma unroll
  for (int m = 0; m < 4; ++m)
#pragma unroll
    for (int r = 0; r < 4; ++r) {
      const int rl = m * 16 + lg * 4 + r;
      const int grow = smap[rl];
      const size_t row = grow < 0 ? 0 : (size_t)grow;
      float part = 0.f;
#pragma unroll
      for (int n = 0; n < 4; ++n) {
        const int col = col0 + n * 16 + lr;
        float v = acc[m][n][r];
        v = v > 0.f ? v : 0.f;
        v = 0.2f * v + 0.8f * X[row * NC + col];
        acc[m][n][r] = v;
        part += v * v;
      }
      part += __shfl_xor(part, 1, 64);
      part += __shfl_xor(part, 2, 64);
      part += __shfl_xor(part, 4, 64);
      part += __shfl_xor(part, 8, 64);
      if (lr == 0) rssq[w][rl] = part;
    }
  __syncthreads();
#pragma unroll
  for (int m = 0; m < 4; ++m)
#pragma unroll
    for (int r = 0; r < 4; ++r) {
      const int rl = m * 16 + lg * 4 + r;
      const int grow = smap[rl];
      if (grow < 0) continue;
      float tot = 0.f;
#pragma unroll
      for (int ww = 0; ww < 8; ++ww) tot += rssq[ww][rl];
      const float inv = 1.0f / sqrtf(tot);
#pragma unroll
      for (int n = 0; n < 4; ++n) {
        const int col = col0 + n * 16 + lr;
        Fbf[(size_t)grow * NC + col] = (bf16)(acc[m][n][r] * inv);
      }
    }
}

// ---------------------------------------------------------------------------
// gemm3 (champion structure + B-direct-from-L2): 128x128 tile, BK=32,
// 256 thr. Only A is LDS-staged (2 gld16/thread per K-step — drain depth
// halved); B fragments read directly from the L2-resident Tbf (1.4 MB) into
// registers — the adapter-proven W2 pattern. LDS 16 KB + launch_bounds
// (256,4) -> ~4 blocks/CU co-resident.
// ---------------------------------------------------------------------------
__global__ __launch_bounds__(256, 4) void k_gemm3(
    const bf16* __restrict__ Fbf, const bf16* __restrict__ Tbf,
    const float* __restrict__ lsc, float* __restrict__ out)
{
  __shared__ bf16 As[2][128 * 32];
  const int bx = blockIdx.x, by = blockIdx.y;
  const int t = threadIdx.x, w = t >> 6, l = t & 63;
  const int wr = w >> 1, wc = w & 1;
  const int lr = l & 15, lg = l >> 4;
  const int row0 = bx * 128, col0 = by * 128;
  const bf16* Ag = Fbf + (size_t)row0 * NC;
  const bf16* BgF = Tbf + (size_t)(col0 + wc * 64 + lr) * NC + lg * 8;  // frag base

#define STG3(buf, kt)                                                         \
  {                                                                           \
    _Pragma("unroll")                                                         \
    for (int i = 0; i < 2; ++i) {                                             \
      const int off = (i * 256 + t) * 16;                                     \
      const int row = off >> 6;                                               \
      const int src = (off & 63) ^ (((row >> 1) & 3) << 4);                   \
      gld16(Ag + (size_t)row * NC + (size_t)(kt) * 32 + (src >> 1),           \
            (char*)As[buf] + off);                                            \
    }                                                                         \
  }

  f32x4 acc[4][4] = {};
  STG3(0, 0);
#pragma unroll 1
  for (int ks = 0; ks < 16; ++ks) {
    const int cur = ks & 1;
    // B fragments direct from L2 (no barrier dependency — compiler waits
    // with its own counted vmcnt before the MFMAs)
    bf16x8 b[4];
#pragma unroll
    for (int n = 0; n < 4; ++n)
      b[n] = *(const bf16x8*)(BgF + (size_t)(n * 16) * NC + ks * 32);
    __syncthreads();                     // A tile ks landed (all waves)
    if (ks + 1 < 16) STG3(cur ^ 1, ks + 1);
    bf16x8 a[4];
#pragma unroll
    for (int m = 0; m < 4; ++m) {
      const int r = wr * 64 + m * 16 + lr;
      a[m] = *(const bf16x8*)&As[cur][r * 32 + ((lg * 8) ^ (((r >> 1) & 3) << 3))];
    }
#pragma unroll
    for (int m = 0; m < 4; ++m)
#pragma unroll
      for (int n = 0; n < 4; ++n)
        acc[m][n] = MFMA(a[m], b[n], acc[m][n]);
  }

  const float s = expf(lsc[0]);
#pragma unroll
  for (int m = 0; m < 4; ++m)
#pragma unroll
    for (int n = 0; n < 4; ++n)
#pragma unroll
      for (int r = 0; r < 4; ++r) {
        const int row = row0 + wr * 64 + m * 16 + lg * 4 + r;
        const int col = col0 + wc * 64 + n * 16 + lr;
        if (col < NT) out[(size_t)row * NT + col] = s * acc[m][n][r];
      }
#undef STG3
}

// ---------------------------------------------------------------------------
extern "C" void kernel_launch(void* const* d_in, const int* in_sizes, int n_in,
                              void* d_out, int out_size, void* d_ws, size_t ws_size,
                              hipStream_t stream) {
  const float* X   = (const float*)d_in[0];
  const int*   lab = (const int*)d_in[1];
  const float* W1  = (const float*)d_in[2];
  const float* W2  = (const float*)d_in[3];
  const float* txt = (const float*)d_in[4];
  const float* lsc = (const float*)d_in[5];
  float* out = (float*)d_out;

  char* ws = (char*)d_ws;
  constexpr size_t SZ_W1T = (size_t)ND * NH * NC * 2;
  constexpr size_t SZ_W2T = (size_t)ND * NC * NH * 2;
  constexpr size_t SZ_TBF = (size_t)NTP * NC * 2;
  constexpr size_t SZ_FBF = (size_t)NB * NC * 2;
  constexpr size_t SZ_MAP = (size_t)NPMAX * 4;
  bf16* W1t = (bf16*)(ws);
  bf16* W2t = (bf16*)(ws + SZ_W1T);
  bf16* Tbf = (bf16*)(ws + SZ_W1T + SZ_W2T);
  bf16* Fbf = (bf16*)(ws + SZ_W1T + SZ_W2T + SZ_TBF);
  int*  map = (int*)(ws + SZ_W1T + SZ_W2T + SZ_TBF + SZ_FBF);
  int*  dmeta = (int*)(ws + SZ_W1T + SZ_W2T + SZ_TBF + SZ_FBF + SZ_MAP);

  k_prep<<<185, 1024, 0, stream>>>(W1, W2, txt, lab, W1t, W2t, Tbf, map, dmeta);
  k_adapter<<<2 * NTILE, 512, 0, stream>>>(X, W1t, W2t, map, dmeta, Fbf);
  k_gemm3<<<dim3(NB / 128, NTP / 128), 256, 0, stream>>>(Fbf, Tbf, lsc, out);
}

// Round 22
// 87.337 us; speedup vs baseline: 1.2430x; 1.2430x over previous
//
#include <hip/hip_runtime.h>
#include <math.h>

typedef __bf16 bf16;
typedef __attribute__((ext_vector_type(8))) __bf16 bf16x8;
typedef __attribute__((ext_vector_type(4))) __bf16 bf16x4;
typedef __attribute__((ext_vector_type(4))) float f32x4;

#define MFMA(a, b, c) __builtin_amdgcn_mfma_f32_16x16x32_bf16((a), (b), (c), 0, 0, 0)
#define BARR() __builtin_amdgcn_s_barrier()
#define SFEN() __builtin_amdgcn_sched_barrier(0)
#define LGKM0() asm volatile("s_waitcnt lgkmcnt(0)" ::: "memory")

static constexpr int NB = 16384;   // batch
static constexpr int NC = 512;     // feature dim
static constexpr int NH = 128;     // bottleneck
static constexpr int ND = 3;       // domains
static constexpr int NT = 1380;    // text rows
static constexpr int NTP = 1408;   // padded to 11 x 128
static constexpr int NTILE = 131;  // max 128-row packed tiles
static constexpr int NPMAX = NTILE * 128;

__device__ __forceinline__ void gld16(const bf16* g, void* l) {
  __builtin_amdgcn_global_load_lds(
      (const __attribute__((address_space(1))) void*)g,
      (__attribute__((address_space(3))) void*)l, 16, 0, 0);
}

// ---------------------------------------------------------------------------
// k_prep (merged prep + sort, 1024-thread blocks, 185 blocks — champion)
// ---------------------------------------------------------------------------
__global__ __launch_bounds__(1024) void k_prep(
    const float* __restrict__ W1, const float* __restrict__ W2,
    const float* __restrict__ txt, const int* __restrict__ lab,
    bf16* __restrict__ W1t, bf16* __restrict__ W2t, bf16* __restrict__ Tbf,
    int* __restrict__ map, int* __restrict__ dmeta)
{
  __shared__ float tl[64][65];
  __shared__ int woff[16][3];
  __shared__ int segbase[4];
  __shared__ int padded[3];
  const int b = blockIdx.x, t = threadIdx.x;

  if (b < 88) {
    const int wv = t >> 6, lane = t & 63;
    const int row = b * 16 + wv;
    bf16x4* dst = (bf16x4*)(Tbf + (size_t)row * NC);
    if (row < NT) {
      const float4* src = (const float4*)(txt + (size_t)row * NC);
      float4 u0 = src[lane * 2], u1 = src[lane * 2 + 1];
      float ssq = u0.x * u0.x + u0.y * u0.y + u0.z * u0.z + u0.w * u0.w +
                  u1.x * u1.x + u1.y * u1.y + u1.z * u1.z + u1.w * u1.w;
      for (int m = 32; m; m >>= 1) ssq += __shfl_xor(ssq, m, 64);
      float inv = 1.0f / sqrtf(ssq);
      bf16x4 o0 = {(bf16)(u0.x * inv), (bf16)(u0.y * inv), (bf16)(u0.z * inv), (bf16)(u0.w * inv)};
      bf16x4 o1 = {(bf16)(u1.x * inv), (bf16)(u1.y * inv), (bf16)(u1.z * inv), (bf16)(u1.w * inv)};
      dst[lane * 2] = o0; dst[lane * 2 + 1] = o1;
    } else {
      bf16x4 z = {(bf16)0.f, (bf16)0.f, (bf16)0.f, (bf16)0.f};
      dst[lane * 2] = z; dst[lane * 2 + 1] = z;
    }
  } else if (b < 136) {
    const int e = b - 88, d = e >> 4, rem = e & 15;
    const int i0 = (rem >> 1) * 64, n0 = (rem & 1) * 64;
    const int rr = t >> 4, c4 = (t & 15) * 4;
    const float* src = W1 + (size_t)d * NC * NH;
    float4 v = *(const float4*)&src[(size_t)(i0 + rr) * NH + n0 + c4];
    tl[rr][c4] = v.x; tl[rr][c4 + 1] = v.y; tl[rr][c4 + 2] = v.z; tl[rr][c4 + 3] = v.w;
    __syncthreads();
    bf16* dst = W1t + (size_t)d * NH * NC;
    bf16x4 o = {(bf16)tl[c4][rr], (bf16)tl[c4 + 1][rr],
                (bf16)tl[c4 + 2][rr], (bf16)tl[c4 + 3][rr]};
    *(bf16x4*)&dst[(size_t)(n0 + rr) * NC + i0 + c4] = o;
  } else if (b < 184) {
    const int e = b - 136, d = e >> 4, rem = e & 15;
    const int j0 = (rem >> 3) * 64, n0 = (rem & 7) * 64;
    const int rr = t >> 4, c4 = (t & 15) * 4;
    const float* src = W2 + (size_t)d * NH * NC;
    float4 v = *(const float4*)&src[(size_t)(j0 + rr) * NC + n0 + c4];
    tl[rr][c4] = v.x; tl[rr][c4 + 1] = v.y; tl[rr][c4 + 2] = v.z; tl[rr][c4 + 3] = v.w;
    __syncthreads();
    bf16* dst = W2t + (size_t)d * NC * NH;
    bf16x4 o = {(bf16)tl[c4][rr], (bf16)tl[c4 + 1][rr],
                (bf16)tl[c4 + 2][rr], (bf16)tl[c4 + 3][rr]};
    *(bf16x4*)&dst[(size_t)(n0 + rr) * NH + j0 + c4] = o;
  } else {
    const int lane = t & 63, wv = t >> 6;
    int c[3] = {0, 0, 0};
    int ld[16];
    const int base = t * 16;
#pragma unroll
    for (int i = 0; i < 16; ++i) { ld[i] = lab[base + i]; c[ld[i]]++; }
    int exc[3];
#pragma unroll
    for (int d = 0; d < 3; ++d) {
      int v = c[d];
      for (int off = 1; off < 64; off <<= 1) {
        int u = __shfl_up(v, off, 64);
        if (lane >= off) v += u;
      }
      exc[d] = v - c[d];
      if (lane == 63) woff[wv][d] = v;
    }
    __syncthreads();
    if (t == 0) {
      int tot[3] = {0, 0, 0};
      for (int w = 0; w < 16; ++w)
        for (int d = 0; d < 3; ++d) { int v = woff[w][d]; woff[w][d] = tot[d]; tot[d] += v; }
      int s = 0;
      for (int d = 0; d < 3; ++d) {
        padded[d] = (tot[d] + 127) & ~127;
        segbase[d] = s; s += padded[d];
      }
      segbase[3] = s;
      dmeta[NTILE] = s;
    }
    __syncthreads();
    for (int tile = t; tile < NTILE; tile += 1024) {
      const int slot = tile * 128;
      int dd = -1;
      for (int d = 0; d < 3; ++d)
        if (slot >= segbase[d] && slot < segbase[d] + padded[d]) dd = d;
      dmeta[tile] = dd;
    }
    for (int i = t; i < NPMAX; i += 1024) map[i] = -1;
    __syncthreads();
    int pos[3];
#pragma unroll
    for (int d = 0; d < 3; ++d) pos[d] = segbase[d] + woff[wv][d] + exc[d];
#pragma unroll
    for (int i = 0; i < 16; ++i) { int d = ld[i]; map[pos[d]++] = base + i; }
  }
}

// ---------------------------------------------------------------------------
// k_adapter (champion: 64-row tiles, 512 thr, 262 blocks, W1 prefetched).
// ---------------------------------------------------------------------------
__global__ __launch_bounds__(512) void k_adapter(
    const float* __restrict__ X, const bf16* __restrict__ W1t,
    const bf16* __restrict__ W2t, const int* __restrict__ map,
    const int* __restrict__ dmeta, bf16* __restrict__ Fbf)
{
  __shared__ bf16 As[2][64 * 64];
  __shared__ bf16 Hs[64 * 128];
  __shared__ float rssq[8][64];
  __shared__ int smap[64];
  const int bx = blockIdx.x;
  const int d = dmeta[bx >> 1];
  if (d < 0) return;
  const int t = threadIdx.x, w = t >> 6, l = t & 63;
  const int lr = l & 15, lg = l >> 4;
  const int row0 = bx * 64;
  if (t < 64) smap[t] = map[row0 + t];

  const bf16* W1B = W1t + (size_t)d * NH * NC + (size_t)(w * 16 + lr) * NC;
  bf16x8 w1f[16];
#pragma unroll
  for (int kt = 0; kt < 8; ++kt)
#pragma unroll
    for (int h = 0; h < 2; ++h)
      w1f[kt * 2 + h] = *(const bf16x8*)(W1B + kt * 64 + h * 32 + lg * 8);

  int arow = map[row0 + (t >> 3)]; if (arow < 0) arow = 0;
  const float4* Xr = (const float4*)(X + (size_t)arow * NC);
  const int f4b = (t & 7) * 2;
  const int wrow = t >> 3;
  const int wcb = ((t & 7) * 16) ^ ((wrow & 7) << 4);

  float4 R0a, R0b, R1a, R1b;
#define LOADR0(kt) { R0a = Xr[(kt) * 16 + f4b]; R0b = Xr[(kt) * 16 + f4b + 1]; }
#define LOADR1(kt) { R1a = Xr[(kt) * 16 + f4b]; R1b = Xr[(kt) * 16 + f4b + 1]; }
#define CVTW(buf, Ra, Rb) {                                                   \
    bf16x8 v_;                                                                \
    v_[0] = (bf16)Ra.x; v_[1] = (bf16)Ra.y; v_[2] = (bf16)Ra.z;               \
    v_[3] = (bf16)Ra.w; v_[4] = (bf16)Rb.x; v_[5] = (bf16)Rb.y;               \
    v_[6] = (bf16)Rb.z; v_[7] = (bf16)Rb.w;                                   \
    *(bf16x8*)((char*)As[buf] + wrow * 128 + wcb) = v_; }

  f32x4 acc1[4] = {};
  LOADR0(0); LOADR1(1);
  CVTW(0, R0a, R0b);
  LOADR0(2);
  LGKM0(); BARR(); SFEN();
#pragma unroll
  for (int kt = 0; kt < 8; ++kt) {
    const int cur = kt & 1;
    if (kt + 1 < 8) {
      if (cur == 0) { CVTW(1, R1a, R1b); if (kt + 3 < 8) LOADR1(kt + 3); }
      else          { CVTW(0, R0a, R0b); if (kt + 3 < 8) LOADR0(kt + 3); }
    }
#pragma unroll
    for (int h = 0; h < 2; ++h) {
      bf16x8 a[4];
#pragma unroll
      for (int m = 0; m < 4; ++m) {
        const int r = m * 16 + lr;
        a[m] = *(const bf16x8*)((const char*)As[cur] +
                                r * 128 + ((h * 64 + lg * 16) ^ ((r & 7) << 4)));
      }
#pragma unroll
      for (int m = 0; m < 4; ++m) acc1[m] = MFMA(a[m], w1f[kt * 2 + h], acc1[m]);
    }
    LGKM0(); SFEN(); BARR(); SFEN();
  }
#undef LOADR0
#undef LOADR1
#undef CVTW

#pragma unroll
  for (int m = 0; m < 4; ++m)
#pragma unroll
    for (int r = 0; r < 4; ++r) {
      const int row = m * 16 + lg * 4 + r;
      const int colb = (w * 16 + lr) * 2;
      const float v = acc1[m][r];
      *(bf16*)((char*)Hs + row * 256 + (colb ^ ((row & 7) << 4))) =
          (bf16)(v > 0.f ? v : 0.f);
    }
  __syncthreads();

  f32x4 acc[4][4] = {};
  const bf16* W2B = W2t + (size_t)d * NC * NH + (size_t)(w * 64) * NH;
#pragma unroll
  for (int ks = 0; ks < 4; ++ks) {
    bf16x8 a[4], bq[4];
#pragma unroll
    for (int m = 0; m < 4; ++m) {
      const int r = m * 16 + lr;
      a[m] = *(const bf16x8*)((const char*)Hs +
                              r * 256 + ((ks * 64 + lg * 16) ^ ((r & 7) << 4)));
    }
#pragma unroll
    for (int n = 0; n < 4; ++n)
      bq[n] = *(const bf16x8*)(W2B + (size_t)(n * 16 + lr) * NH + ks * 32 + lg * 8);
#pragma unroll
    for (int m = 0; m < 4; ++m)
#pragma unroll
      for (int n = 0; n < 4; ++n)
        acc[m][n] = MFMA(a[m], bq[n], acc[m][n]);
  }

  const int col0 = w * 64;
#pragma unroll
  for (int m = 0; m < 4; ++m)
#pragma unroll
    for (int r = 0; r < 4; ++r) {
      const int rl = m * 16 + lg * 4 + r;
      const int grow = smap[rl];
      const size_t row = grow < 0 ? 0 : (size_t)grow;
      float part = 0.f;
#pragma unroll
      for (int n = 0; n < 4; ++n) {
        const int col = col0 + n * 16 + lr;
        float v = acc[m][n][r];
        v = v > 0.f ? v : 0.f;
        v = 0.2f * v + 0.8f * X[row * NC + col];
        acc[m][n][r] = v;
        part += v * v;
      }
      part += __shfl_xor(part, 1, 64);
      part += __shfl_xor(part, 2, 64);
      part += __shfl_xor(part, 4, 64);
      part += __shfl_xor(part, 8, 64);
      if (lr == 0) rssq[w][rl] = part;
    }
  __syncthreads();
#pragma unroll
  for (int m = 0; m < 4; ++m)
#pragma unroll
    for (int r = 0; r < 4; ++r) {
      const int rl = m * 16 + lg * 4 + r;
      const int grow = smap[rl];
      if (grow < 0) continue;
      float tot = 0.f;
#pragma unroll
      for (int ww = 0; ww < 8; ++ww) tot += rssq[ww][rl];
      const float inv = 1.0f / sqrtf(tot);
#pragma unroll
      for (int n = 0; n < 4; ++n) {
        const int col = col0 + n * 16 + lr;
        Fbf[(size_t)grow * NC + col] = (bf16)(acc[m][n][r] * inv);
      }
    }
}

// ---------------------------------------------------------------------------
// gemm3 (champion: 128x128 tile, BK=32, 256 thr, double-buffered sync-drain,
// verified 0-conflict swizzle — measured optimum across 11 variants).
// ---------------------------------------------------------------------------
__global__ __launch_bounds__(256) void k_gemm3(
    const bf16* __restrict__ Fbf, const bf16* __restrict__ Tbf,
    const float* __restrict__ lsc, float* __restrict__ out)
{
  __shared__ bf16 As[2][128 * 32];
  __shared__ bf16 Bs[2][128 * 32];
  const int bx = blockIdx.x, by = blockIdx.y;
  const int t = threadIdx.x, w = t >> 6, l = t & 63;
  const int wr = w >> 1, wc = w & 1;
  const int lr = l & 15, lg = l >> 4;
  const int row0 = bx * 128, col0 = by * 128;
  const bf16* Ag = Fbf + (size_t)row0 * NC;
  const bf16* Bg = Tbf + (size_t)col0 * NC;

#define STG3(buf, kt)                                                         \
  {                                                                           \
    _Pragma("unroll")                                                         \
    for (int i = 0; i < 2; ++i) {                                             \
      const int off = (i * 256 + t) * 16;                                     \
      const int row = off >> 6;                                               \
      const int src = (off & 63) ^ (((row >> 1) & 3) << 4);                   \
      const size_t go = (size_t)row * NC + (size_t)(kt) * 32 + (src >> 1);    \
      gld16(Ag + go, (char*)As[buf] + off);                                   \
      gld16(Bg + go, (char*)Bs[buf] + off);                                   \
    }                                                                         \
  }

  f32x4 acc[4][4] = {};
  STG3(0, 0);
#pragma unroll 1
  for (int ks = 0; ks < 16; ++ks) {
    const int cur = ks & 1;
    __syncthreads();
    if (ks + 1 < 16) STG3(cur ^ 1, ks + 1);
    bf16x8 a[4], b[4];
#pragma unroll
    for (int m = 0; m < 4; ++m) {
      const int r = wr * 64 + m * 16 + lr;
      a[m] = *(const bf16x8*)&As[cur][r * 32 + ((lg * 8) ^ (((r >> 1) & 3) << 3))];
    }
#pragma unroll
    for (int n = 0; n < 4; ++n) {
      const int r = wc * 64 + n * 16 + lr;
      b[n] = *(const bf16x8*)&Bs[cur][r * 32 + ((lg * 8) ^ (((r >> 1) & 3) << 3))];
    }
#pragma unroll
    for (int m = 0; m < 4; ++m)
#pragma unroll
      for (int n = 0; n < 4; ++n)
        acc[m][n] = MFMA(a[m], b[n], acc[m][n]);
  }

  const float s = expf(lsc[0]);
#pragma unroll
  for (int m = 0; m < 4; ++m)
#pragma unroll
    for (int n = 0; n < 4; ++n)
#pragma unroll
      for (int r = 0; r < 4; ++r) {
        const int row = row0 + wr * 64 + m * 16 + lg * 4 + r;
        const int col = col0 + wc * 64 + n * 16 + lr;
        if (col < NT) out[(size_t)row * NT + col] = s * acc[m][n][r];
      }
#undef STG3
}

// ---------------------------------------------------------------------------
extern "C" void kernel_launch(void* const* d_in, const int* in_sizes, int n_in,
                              void* d_out, int out_size, void* d_ws, size_t ws_size,
                              hipStream_t stream) {
  const float* X   = (const float*)d_in[0];
  const int*   lab = (const int*)d_in[1];
  const float* W1  = (const float*)d_in[2];
  const float* W2  = (const float*)d_in[3];
  const float* txt = (const float*)d_in[4];
  const float* lsc = (const float*)d_in[5];
  float* out = (float*)d_out;

  char* ws = (char*)d_ws;
  constexpr size_t SZ_W1T = (size_t)ND * NH * NC * 2;   //    393,216
  constexpr size_t SZ_W2T = (size_t)ND * NC * NH * 2;   //    393,216
  constexpr size_t SZ_TBF = (size_t)NTP * NC * 2;       //  1,441,792
  constexpr size_t SZ_FBF = (size_t)NB * NC * 2;        // 16,777,216
  constexpr size_t SZ_MAP = (size_t)NPMAX * 4;          //     67,072
  bf16* W1t = (bf16*)(ws);
  bf16* W2t = (bf16*)(ws + SZ_W1T);
  bf16* Tbf = (bf16*)(ws + SZ_W1T + SZ_W2T);
  bf16* Fbf = (bf16*)(ws + SZ_W1T + SZ_W2T + SZ_TBF);
  int*  map = (int*)(ws + SZ_W1T + SZ_W2T + SZ_TBF + SZ_FBF);
  int*  dmeta = (int*)(ws + SZ_W1T + SZ_W2T + SZ_TBF + SZ_FBF + SZ_MAP);

  k_prep<<<185, 1024, 0, stream>>>(W1, W2, txt, lab, W1t, W2t, Tbf, map, dmeta);
  k_adapter<<<2 * NTILE, 512, 0, stream>>>(X, W1t, W2t, map, dmeta, Fbf);
  k_gemm3<<<dim3(NB / 128, NTP / 128), 256, 0, stream>>>(Fbf, Tbf, lsc, out);
}